// Round 9
// baseline (121.746 us; speedup 1.0000x reference)
//
#include <hip/hip_runtime.h>
#include <math.h>

#define Bn 64
#define QLn 40
#define ALn 60
#define Dn 300
#define KS 640       /* stored row width: [hi(320) | lo(320)] */
#define NQ 1024      /* Q job cols: 768 sm-conv | 256 attnW2 */
#define NA 1536      /* A job cols: 768 sm-conv | 768 ctx-conv */

typedef __attribute__((ext_vector_type(8))) short bf16x8;
typedef __attribute__((ext_vector_type(4))) float f32x4;

__device__ __forceinline__ float bf2f(unsigned short s) {
  return __uint_as_float(((unsigned)s) << 16);
}
__device__ __forceinline__ short f2bf(float f) {
  unsigned u = __float_as_uint(f);
  unsigned r = (u + 0x7FFFu + ((u >> 16) & 1u)) >> 16;
  return (short)r;
}

// ============ fused prep ============
// bid [0,1600): gather -> split-bf16 [hi|lo] + row norms
// bid [1600,1800): BT transpose (coalesced, LDS tile)
// bid [1800,2057): Wcat = [ctxfcW | ctxfcW@attnW0] + bvec
// bid 2057: zero num/den/logits/done (per-launch, before k_fcattn/k_w1bn atomics)
__global__ __launch_bounds__(256) void k_prep(
    const int* __restrict__ qIdx, const int* __restrict__ aIdx,
    const float* __restrict__ emb,
    const float* __restrict__ smW, const float* __restrict__ ctxW,
    const float* __restrict__ attnW, const float* __restrict__ ctxfcW,
    const float* __restrict__ ctxfcb, const float* __restrict__ attnb,
    short* __restrict__ Ae1, short* __restrict__ Ae2,
    float* __restrict__ nq, float* __restrict__ na,
    short* __restrict__ BTall, float* __restrict__ Wcat, float* __restrict__ bvec,
    float* __restrict__ numb, float* __restrict__ denb,
    float* __restrict__ logits, int* __restrict__ done) {
  __shared__ float lds[4160];
  int bid = blockIdx.x, tid = threadIdx.x;
  int w = tid >> 6, lane = tid & 63;
  if (bid < 1600) {
    int row = bid * 4 + w;
    const int* idxp; short* Ae; float* nrm; int r;
    if (row < 2560) { idxp = qIdx; Ae = Ae1; nrm = nq; r = row; }
    else { idxp = aIdx; Ae = Ae2; nrm = na; r = row - 2560; }
    int tok = idxp[r];
    const float4* src = (const float4*)(emb + (size_t)tok * Dn);
    short* d = Ae + (size_t)r * KS;
    float ssq = 0.f;
    for (int i = lane; i < 80; i += 64) {
      float4 v = (i < 75) ? src[i] : make_float4(0.f, 0.f, 0.f, 0.f);
      ssq += v.x * v.x + v.y * v.y + v.z * v.z + v.w * v.w;
      short4 h4, l4v;
      h4.x = f2bf(v.x); l4v.x = f2bf(v.x - bf2f((unsigned short)h4.x));
      h4.y = f2bf(v.y); l4v.y = f2bf(v.y - bf2f((unsigned short)h4.y));
      h4.z = f2bf(v.z); l4v.z = f2bf(v.z - bf2f((unsigned short)h4.z));
      h4.w = f2bf(v.w); l4v.w = f2bf(v.w - bf2f((unsigned short)h4.w));
      *(short4*)&d[i * 4] = h4;
      *(short4*)&d[320 + i * 4] = l4v;
    }
    #pragma unroll
    for (int o = 32; o; o >>= 1) ssq += __shfl_down(ssq, o, 64);
    if (lane == 0) nrm[r] = sqrtf(ssq);
  } else if (bid < 1800) {
    int tb = bid - 1600;
    int kt = tb % 5, nt = tb / 5;
    int n0 = nt * 64;
    const float* src; int cb;
    if (n0 < 768)       { src = smW + (n0 >> 8) * 76800; cb = n0 & 255; }
    else if (n0 < 1024) { src = attnW + 65536;           cb = n0 - 768; }
    else if (n0 < 1792) { int m = n0 - 1024; src = smW + (m >> 8) * 76800; cb = m & 255; }
    else                { int m = n0 - 1792; src = ctxW + (m >> 8) * 76800; cb = m & 255; }
    float* tile = lds;   // [64][65]
    int nn = tid & 63;
    #pragma unroll
    for (int it = 0; it < 16; ++it) {
      int kl = it * 4 + w;
      int k = kt * 64 + kl;
      tile[kl * 65 + nn] = (k < 300) ? src[(size_t)k * 256 + cb + nn] : 0.f;
    }
    __syncthreads();
    #pragma unroll
    for (int it = 0; it < 16; ++it) {
      int nloc = it * 4 + w;
      int kl = tid & 63;
      float v = tile[kl * 65 + nloc];
      int n = n0 + nloc, k = kt * 64 + kl;
      short hi = f2bf(v), lo = f2bf(v - bf2f((unsigned short)hi));
      BTall[(size_t)n * KS + k] = hi;
      BTall[(size_t)n * KS + 320 + k] = lo;
    }
  } else if (bid < 2057) {
    int k = bid - 1800;            // 0..256
    float* rowv = lds;
    int j = tid;
    rowv[j] = (k < 256) ? ctxfcW[(size_t)k * 256 + j] : ctxfcb[j];
    __syncthreads();
    float a0 = 0.f, a1 = 0.f, a2 = 0.f, a3 = 0.f;
    for (int m = 0; m < 256; m += 4) {
      a0 += rowv[m]     * attnW[(size_t)m * 256 + j];
      a1 += rowv[m + 1] * attnW[(size_t)(m + 1) * 256 + j];
      a2 += rowv[m + 2] * attnW[(size_t)(m + 2) * 256 + j];
      a3 += rowv[m + 3] * attnW[(size_t)(m + 3) * 256 + j];
    }
    float acc = (a0 + a1) + (a2 + a3);
    if (k < 256) {
      Wcat[(size_t)k * 512 + j] = rowv[j];
      Wcat[(size_t)k * 512 + 256 + j] = acc;
    } else {
      bvec[j] = ctxfcb[j];
      bvec[256 + j] = acc + attnb[j];
    }
  } else {
    // ---- zero accumulators used by later atomics ----
    for (int i = tid; i < Bn * 256; i += 256) numb[i] = 0.f;
    if (tid < Bn) denb[tid] = 0.f;
    if (tid < 2 * Bn) logits[tid] = 0.f;
    if (tid == 0) *done = 0;
  }
}

// ============ split mega MFMA GEMM (bf16 out) + MFMA cosine ============
__device__ __forceinline__ void gl2lds16(const short* g, short* l) {
  __builtin_amdgcn_global_load_lds(
      (const __attribute__((address_space(1))) unsigned int*)g,
      (__attribute__((address_space(3))) unsigned int*)l, 16, 0, 0);
}

__global__ __launch_bounds__(256) void k_mega(
    const short* __restrict__ Ae1, const short* __restrict__ Ae2,
    const short* __restrict__ BTall, short* __restrict__ ZQb, short* __restrict__ ZAb,
    const float* __restrict__ nq, const float* __restrict__ na,
    float* __restrict__ cosb) {
  __shared__ __align__(16) short As[128 * 32];
  __shared__ __align__(16) short Bs[128 * 32];
  int tid = threadIdx.x;
  int wid = tid >> 6, lane = tid & 63;
  int l15 = lane & 15, l4 = lane >> 4;
  int bid = blockIdx.x;
  int lin = (bid & 7) * 73 + (bid >> 3);   // bijective XCD swizzle, 584 = 8 x 73

  if (lin < 520) {
    const short *A, *BT; short* C; int bx, by, ldc;
    if (lin < 160) {            // Q job: 20 x 8 tiles
      int chunk = lin >> 4, ww = lin & 15;
      by = ww >> 1; bx = chunk * 2 + (ww & 1);
      A = Ae1; BT = BTall; C = ZQb; ldc = NQ;
    } else {                    // A job: 30 x 12 tiles
      int l2 = lin - 160;
      int chunk = l2 / 24, ww = l2 % 24;
      by = ww >> 1; bx = chunk * 2 + (ww & 1);
      A = Ae2; BT = BTall + (size_t)1024 * KS; C = ZAb; ldc = NA;
    }
    int rowBase = bx * 128, colBase = by * 128;
    int mw = wid * 32;

    f32x4 acc[2][8];
    #pragma unroll
    for (int i = 0; i < 2; ++i)
      #pragma unroll
      for (int j = 0; j < 8; ++j) acc[i][j] = (f32x4){0.f, 0.f, 0.f, 0.f};

    int rowA0 = mw + l15, rowA1 = mw + 16 + l15;
    int sA0 = (l4 ^ ((rowA0 >> 1) & 3)) << 3;
    int sA1 = (l4 ^ ((rowA1 >> 1) & 3)) << 3;

    #pragma unroll 1
    for (int g = 0; g < 3; ++g) {
      int aoff = (g == 1) ? 320 : 0;
      int boff = (g == 2) ? 320 : 0;
      #pragma unroll 1
      for (int ks = 0; ks < 10; ++ks) {
        int ka0 = aoff + ks * 32, kb0 = boff + ks * 32;
        #pragma unroll
        for (int j = 0; j < 2; ++j) {
          int idx = tid + j * 256;
          int r = idx >> 2, s = idx & 3;
          int sl = s ^ ((r >> 1) & 3);
          int chunkStart = j * 256 + wid * 64;
          gl2lds16(A + (size_t)(rowBase + r) * KS + ka0 + (sl << 3), &As[chunkStart * 8]);
          gl2lds16(BT + (size_t)(colBase + r) * KS + kb0 + (sl << 3), &Bs[chunkStart * 8]);
        }
        __syncthreads();
        bf16x8 a0 = *reinterpret_cast<const bf16x8*>(&As[rowA0 * 32 + sA0]);
        bf16x8 a1 = *reinterpret_cast<const bf16x8*>(&As[rowA1 * 32 + sA1]);
        #pragma unroll
        for (int nj = 0; nj < 8; ++nj) {
          int rb = nj * 16 + l15;
          bf16x8 bf = *reinterpret_cast<const bf16x8*>(&Bs[rb * 32 + ((l4 ^ ((rb >> 1) & 3)) << 3)]);
          acc[0][nj] = __builtin_amdgcn_mfma_f32_16x16x32_bf16(a0, bf, acc[0][nj], 0, 0, 0);
          acc[1][nj] = __builtin_amdgcn_mfma_f32_16x16x32_bf16(a1, bf, acc[1][nj], 0, 0, 0);
        }
        __syncthreads();
      }
    }
    #pragma unroll
    for (int mi = 0; mi < 2; ++mi) {
      int row0 = rowBase + mw + mi * 16 + l4 * 4;
      #pragma unroll
      for (int nj = 0; nj < 8; ++nj) {
        int col = colBase + nj * 16 + l15;
        #pragma unroll
        for (int r = 0; r < 4; ++r)
          C[(size_t)(row0 + r) * ldc + col] = f2bf(acc[mi][nj][r]);
      }
    }
  } else {
    // ---- cosine job: per-b 64x64 MFMA tile ----
    int b = lin - 520;
    int rowBase = b * 40, colBase = b * 60;
    f32x4 cacc[4];
    #pragma unroll
    for (int nj = 0; nj < 4; ++nj) cacc[nj] = (f32x4){0.f, 0.f, 0.f, 0.f};
    int rowA = (wid << 4) + l15;
    int sA = (l4 ^ ((rowA >> 1) & 3)) << 3;

    #pragma unroll 1
    for (int g = 0; g < 3; ++g) {
      int aoff = (g == 1) ? 320 : 0;
      int boff = (g == 2) ? 320 : 0;
      #pragma unroll 1
      for (int ks = 0; ks < 10; ++ks) {
        int ka0 = aoff + ks * 32, kb0 = boff + ks * 32;
        int r = tid >> 2, s = tid & 3;
        int sl = s ^ ((r >> 1) & 3);
        int chunkStart = wid * 64;
        int gr = rowBase + r; if (gr > 2559) gr = 2559;
        int gc = colBase + r; if (gc > 3839) gc = 3839;
        gl2lds16(Ae1 + (size_t)gr * KS + ka0 + (sl << 3), &As[chunkStart * 8]);
        gl2lds16(Ae2 + (size_t)gc * KS + kb0 + (sl << 3), &Bs[chunkStart * 8]);
        __syncthreads();
        bf16x8 a0 = *reinterpret_cast<const bf16x8*>(&As[rowA * 32 + sA]);
        #pragma unroll
        for (int nj = 0; nj < 4; ++nj) {
          int rb = (nj << 4) + l15;
          bf16x8 bf = *reinterpret_cast<const bf16x8*>(&Bs[rb * 32 + ((l4 ^ ((rb >> 1) & 3)) << 3)]);
          cacc[nj] = __builtin_amdgcn_mfma_f32_16x16x32_bf16(a0, bf, cacc[nj], 0, 0, 0);
        }
        __syncthreads();
      }
    }
    int q0 = (wid << 4) + l4 * 4;
    #pragma unroll
    for (int nj = 0; nj < 4; ++nj) {
      int a = (nj << 4) + l15;
      if (a >= ALn) continue;
      float nav = na[colBase + a];
      #pragma unroll
      for (int r = 0; r < 4; ++r) {
        int qq = q0 + r;
        if (qq < QLn) {
          float den = fmaxf(nq[rowBase + qq] * nav, 1e-6f);
          cosb[(size_t)(rowBase + qq) * ALn + a] = cacc[nj][r] / den;
        }
      }
    }
  }
}

// ============ fused: sm-pool+fc (32 blocks) | ctx-pool+attn-MLP+score+num/den (320) ============
__global__ __launch_bounds__(256) void k_fcattn(
    const short* __restrict__ ZQb, const short* __restrict__ ZAb,
    const float* __restrict__ convb, const float* __restrict__ smfcW,
    const float* __restrict__ smfcb, const float* __restrict__ cosb,
    const float* __restrict__ ctxb, const float* __restrict__ Wcat,
    const float* __restrict__ bvec, const float* __restrict__ probW,
    float* __restrict__ feat_comb, float* __restrict__ numb, float* __restrict__ denb) {
  __shared__ float lds[10816];   // xin[2048] | wt[8192] | sred[64] | cl[512]
  int bid = blockIdx.x, j = threadIdx.x;
  if (bid < 32) {
    // ---- sm pool (in-block) + fc -> feat_comb[64][512] ----
    float* xin = lds;            // [256][4]
    float* wt  = lds + 1024;     // [32][256]
    int r0 = bid * 4;
    float bias0 = convb[j];
    #pragma unroll
    for (int rr = 0; rr < 4; ++rr) {
      int s = r0 + rr;
      const short* zb; int L, ld;
      if (s < Bn) { zb = ZQb + (size_t)s * QLn * NQ; L = QLn; ld = NQ; }
      else        { zb = ZAb + (size_t)(s - Bn) * ALn * NA; L = ALn; ld = NA; }
      float m = 0.f;
      for (int t = 0; t <= L - 3; ++t) {
        float v = bias0 + bf2f((unsigned short)zb[t * ld + j])
                        + bf2f((unsigned short)zb[(t + 1) * ld + 256 + j])
                        + bf2f((unsigned short)zb[(t + 2) * ld + 512 + j]);
        m = fmaxf(m, v);
      }
      xin[j * 4 + rr] = m;
    }
    float acc[4];
    #pragma unroll
    for (int rr = 0; rr < 4; ++rr) acc[rr] = smfcb[j];
    for (int ph = 0; ph < 8; ++ph) {
      const float4* src = (const float4*)(smfcW + (size_t)ph * 32 * 256);
      float4* dst = (float4*)wt;
      #pragma unroll
      for (int i = 0; i < 8; ++i) dst[i * 256 + j] = src[i * 256 + j];
      __syncthreads();
      #pragma unroll
      for (int kk = 0; kk < 32; ++kk) {
        float4 x = *reinterpret_cast<const float4*>(&xin[(ph * 32 + kk) * 4]);
        float wv = wt[kk * 256 + j];
        acc[0] += x.x * wv; acc[1] += x.y * wv; acc[2] += x.z * wv; acc[3] += x.w * wv;
      }
      __syncthreads();
    }
    #pragma unroll
    for (int rr = 0; rr < 4; ++rr) {
      int row = r0 + rr;
      feat_comb[(size_t)(row & 63) * 512 + ((row >> 6) * 256) + j] = acc[rr];
    }
  } else {
    // ---- ctx pool (in-block) + attn MLP + score + softmax-num/den atomics ----
    float* xin  = lds;           // [256][8]
    float* wt   = lds + 2048;    // [16][512]
    float* sred = lds + 10240;   // [8][4]
    float* cl   = lds + 10304;   // [8][60]
    int g = bid - 32;
    int b = g / 5, q0 = (g % 5) * 8;
    int rq = b * QLn + q0;
    for (int i = j; i < 8 * ALn; i += 256)
      cl[(i / ALn) * ALn + (i % ALn)] = cosb[(size_t)(rq + i / ALn) * ALn + (i % ALn)];
    __syncthreads();
    const short* zb = ZAb + (size_t)b * ALn * NA + 768;
    float biasc = ctxb[j];
    float m[8];
    #pragma unroll
    for (int rr = 0; rr < 8; ++rr) m[rr] = 0.f;
    for (int t = 0; t <= ALn - 3; ++t) {
      float v0 = bf2f((unsigned short)zb[t * NA + j]);
      float v1 = bf2f((unsigned short)zb[(t + 1) * NA + 256 + j]);
      float v2 = bf2f((unsigned short)zb[(t + 2) * NA + 512 + j]);
      #pragma unroll
      for (int rr = 0; rr < 8; ++rr) {
        float v = biasc + cl[rr * ALn + t] * v0 + cl[rr * ALn + t + 1] * v1
                        + cl[rr * ALn + t + 2] * v2;
        m[rr] = fmaxf(m[rr], v);
      }
    }
    #pragma unroll
    for (int rr = 0; rr < 8; ++rr) xin[j * 8 + rr] = m[rr];
    float hf[8], hh[8];
    float bf0 = bvec[j], bh0 = bvec[256 + j];
    #pragma unroll
    for (int rr = 0; rr < 8; ++rr) {
      hf[rr] = bf0;
      hh[rr] = bh0 + bf2f((unsigned short)ZQb[(size_t)(rq + rr) * NQ + 768 + j]);
    }
    for (int ph = 0; ph < 16; ++ph) {
      const float4* src = (const float4*)(Wcat + (size_t)ph * 16 * 512);
      float4* dst = (float4*)wt;
      #pragma unroll
      for (int i = 0; i < 8; ++i) dst[i * 256 + j] = src[i * 256 + j];
      __syncthreads();
      #pragma unroll
      for (int kk = 0; kk < 16; ++kk) {
        int k = ph * 16 + kk;
        float4 x0 = *reinterpret_cast<const float4*>(&xin[k * 8]);
        float4 x1 = *reinterpret_cast<const float4*>(&xin[k * 8 + 4]);
        float w0 = wt[kk * 512 + j], w1 = wt[kk * 512 + 256 + j];
        hf[0] += x0.x * w0; hf[1] += x0.y * w0; hf[2] += x0.z * w0; hf[3] += x0.w * w0;
        hf[4] += x1.x * w0; hf[5] += x1.y * w0; hf[6] += x1.z * w0; hf[7] += x1.w * w0;
        hh[0] += x0.x * w1; hh[1] += x0.y * w1; hh[2] += x0.z * w1; hh[3] += x0.w * w1;
        hh[4] += x1.x * w1; hh[5] += x1.y * w1; hh[6] += x1.z * w1; hh[7] += x1.w * w1;
      }
      __syncthreads();
    }
    // scores: s_rr = sum_j tanh(hh)*probW  (bounded |s| <= ~4 -> exp without max-sub)
    float pw = probW[j];
    int lane = j & 63, wv = j >> 6;
    #pragma unroll
    for (int rr = 0; rr < 8; ++rr) {
      float s = tanhf(hh[rr]) * pw;
      #pragma unroll
      for (int off = 32; off; off >>= 1) s += __shfl_down(s, off, 64);
      if (lane == 0) sred[rr * 4 + wv] = s;
    }
    __syncthreads();
    float e[8], esum = 0.f, acc3 = 0.f;
    #pragma unroll
    for (int rr = 0; rr < 8; ++rr) {
      float s = sred[rr * 4] + sred[rr * 4 + 1] + sred[rr * 4 + 2] + sred[rr * 4 + 3];
      e[rr] = __expf(s);
      esum += e[rr];
      acc3 += e[rr] * hf[rr];
    }
    atomicAdd(&numb[(size_t)b * 256 + j], acc3);
    if (j == 0) atomicAdd(&denb[b], esum);
  }
}

// ============ fused W1(+feature3 via num/den) + BN + tanh + head (last block) ============
__global__ __launch_bounds__(256) void k_w1bn(
    const float* __restrict__ feat_comb, const float* __restrict__ numb,
    const float* __restrict__ denb, const float* __restrict__ W1,
    const float* __restrict__ b1, const float* __restrict__ gamma,
    const float* __restrict__ beta, const float* __restrict__ W2,
    const float* __restrict__ b2, float* __restrict__ feat_out,
    float* __restrict__ preds, float* __restrict__ logits, int* __restrict__ done) {
  int j0 = blockIdx.x * 8;
  int tid = threadIdx.x;
  __shared__ float wl[768][12];
  __shared__ float hb[64][8];
  __shared__ int lastflag;
  for (int it = 0; it < 24; ++it) {
    int idx = tid + it * 256;
    int k = idx >> 3, jj = idx & 7;
    wl[k][jj] = W1[(size_t)k * 512 + j0 + jj];
  }
  __syncthreads();
  int n = tid >> 2, p = tid & 3;
  float acc1[8] = {0.f, 0.f, 0.f, 0.f, 0.f, 0.f, 0.f, 0.f};
  float acc2[8] = {0.f, 0.f, 0.f, 0.f, 0.f, 0.f, 0.f, 0.f};
  const float* frow = feat_comb + (size_t)n * 512 + p;
  for (int i = 0; i < 128; ++i) {
    float v = frow[i * 4];
    int k = p + i * 4;
    float4 w0 = *reinterpret_cast<const float4*>(&wl[k][0]);
    float4 w1v = *reinterpret_cast<const float4*>(&wl[k][4]);
    acc1[0] += v * w0.x; acc1[1] += v * w0.y; acc1[2] += v * w0.z; acc1[3] += v * w0.w;
    acc1[4] += v * w1v.x; acc1[5] += v * w1v.y; acc1[6] += v * w1v.z; acc1[7] += v * w1v.w;
  }
  const float* nrow = numb + (size_t)n * 256 + p;
  for (int i = 0; i < 64; ++i) {
    float v = nrow[i * 4];
    int k = 512 + p + i * 4;
    float4 w0 = *reinterpret_cast<const float4*>(&wl[k][0]);
    float4 w1v = *reinterpret_cast<const float4*>(&wl[k][4]);
    acc2[0] += v * w0.x; acc2[1] += v * w0.y; acc2[2] += v * w0.z; acc2[3] += v * w0.w;
    acc2[4] += v * w1v.x; acc2[5] += v * w1v.y; acc2[6] += v * w1v.z; acc2[7] += v * w1v.w;
  }
  #pragma unroll
  for (int jj = 0; jj < 8; ++jj) {
    acc1[jj] += __shfl_xor(acc1[jj], 1, 64);
    acc1[jj] += __shfl_xor(acc1[jj], 2, 64);
    acc2[jj] += __shfl_xor(acc2[jj], 1, 64);
    acc2[jj] += __shfl_xor(acc2[jj], 2, 64);
  }
  if (p == 0) {
    float rden = 1.f / denb[n];
    #pragma unroll
    for (int jj = 0; jj < 8; ++jj) hb[n][jj] = acc1[jj] + rden * acc2[jj] + b1[j0 + jj];
  }
  __syncthreads();
  if (tid < 64) {
    float l0p = 0.f, l1p = 0.f;
    #pragma unroll
    for (int jj = 0; jj < 8; ++jj) {
      float v = hb[tid][jj];
      float s = v;
      #pragma unroll
      for (int off = 32; off; off >>= 1) s += __shfl_xor(s, off, 64);
      float mu = s * (1.f / 64.f);
      float d = v - mu;
      float q2 = d * d;
      #pragma unroll
      for (int off = 32; off; off >>= 1) q2 += __shfl_xor(q2, off, 64);
      float var = q2 * (1.f / 64.f);
      float fo = tanhf(d * rsqrtf(var + 1e-5f) * gamma[j0 + jj] + beta[j0 + jj]);
      feat_out[(size_t)tid * 512 + j0 + jj] = fo;
      l0p += fo * W2[(j0 + jj) * 2 + 0];
      l1p += fo * W2[(j0 + jj) * 2 + 1];
    }
    atomicAdd(&logits[tid * 2 + 0], l0p);
    atomicAdd(&logits[tid * 2 + 1], l1p);
  }
  __threadfence();
  __syncthreads();
  if (tid == 0) lastflag = (atomicAdd(done, 1) == gridDim.x - 1) ? 1 : 0;
  __syncthreads();
  if (lastflag && tid < 64) {
    __threadfence();
    float l0 = atomicAdd(&logits[tid * 2 + 0], 0.f) + b2[0];
    float l1 = atomicAdd(&logits[tid * 2 + 1], 0.f) + b2[1];
    float mx = fmaxf(l0, l1);
    float lse = mx + logf(__expf(l0 - mx) + __expf(l1 - mx));
    preds[tid * 2 + 0] = l0 - lse;
    preds[tid * 2 + 1] = l1 - lse;
  }
}

extern "C" void kernel_launch(void* const* d_in, const int* in_sizes, int n_in,
                              void* d_out, int out_size, void* d_ws, size_t ws_size,
                              hipStream_t stream) {
  (void)in_sizes; (void)n_in; (void)out_size; (void)ws_size;
  const int*   question  = (const int*)d_in[0];
  const int*   answer    = (const int*)d_in[1];
  const float* embedding = (const float*)d_in[3];
  const float* sm_convW  = (const float*)d_in[4];
  const float* sm_convb  = (const float*)d_in[5];
  const float* sm_fcW    = (const float*)d_in[6];
  const float* sm_fcb    = (const float*)d_in[7];
  const float* ctx_convW = (const float*)d_in[8];
  const float* ctx_convb = (const float*)d_in[9];
  const float* ctx_fcW   = (const float*)d_in[10];
  const float* ctx_fcb   = (const float*)d_in[11];
  const float* attnW     = (const float*)d_in[12];
  const float* attnb     = (const float*)d_in[13];
  const float* probW     = (const float*)d_in[14];
  const float* W1        = (const float*)d_in[15];
  const float* b1        = (const float*)d_in[16];
  const float* gamma     = (const float*)d_in[17];
  const float* beta      = (const float*)d_in[18];
  const float* W2        = (const float*)d_in[19];
  const float* b2        = (const float*)d_in[20];

  float* out = (float*)d_out;   // [0:128) preds, [128:) feat_out 64x512
  char* base = (char*)d_ws;
  size_t off = 0;
  auto alloc = [&](size_t bytes) { char* p = base + off; off += (bytes + 255) & ~(size_t)255; return p; };

  short* Ae1   = (short*)alloc(2560ull * KS * 2);      // 3.28 MB
  short* Ae2   = (short*)alloc(3840ull * KS * 2);      // 4.92 MB
  short* BTall = (short*)alloc(2560ull * KS * 2);      // 3.28 MB
  short* ZQb   = (short*)alloc(2560ull * NQ * 2);      // 5.24 MB (bf16)
  short* ZAb   = (short*)alloc(3840ull * NA * 2);      // 11.8 MB (bf16)
  float* nq    = (float*)alloc(2560 * 4);
  float* na    = (float*)alloc(3840 * 4);
  float* cosb  = (float*)alloc(2560ull * ALn * 4);
  float* Wcat  = (float*)alloc(256ull * 512 * 4);
  float* bvec  = (float*)alloc(512 * 4);
  float* feat_comb = (float*)alloc(64ull * 512 * 4);
  float* numb   = (float*)alloc(64ull * 256 * 4);
  float* denb   = (float*)alloc(64 * 4);
  float* logits = (float*)alloc(128 * 4);
  int*   done   = (int*)alloc(256);

  // 1. prep: gather+norms | BT-transpose | Wcat | zero-accumulators (2058 blocks)
  k_prep<<<2058, 256, 0, stream>>>(question, answer, embedding, sm_convW, ctx_convW,
                                   attnW, ctx_fcW, ctx_fcb, attnb,
                                   Ae1, Ae2, nq, na, BTall, Wcat, bvec,
                                   numb, denb, logits, done);
  // 2. split mega GEMM (bf16 out) + MFMA cosine (584 blocks)
  k_mega<<<584, 256, 0, stream>>>(Ae1, Ae2, BTall, ZQb, ZAb, nq, na, cosb);
  // 3. pools + fc | ctx-fc + attn + score + softmax num/den (352 blocks)
  k_fcattn<<<352, 256, 0, stream>>>(ZQb, ZAb, sm_convb, sm_fcW, sm_fcb, cosb,
                                    ctx_convb, Wcat, bvec, probW,
                                    feat_comb, numb, denb);
  // 4. W1 + feature3 + BN + tanh + head (64 blocks, last-block log_softmax)
  k_w1bn<<<64, 256, 0, stream>>>(feat_comb, numb, denb, W1, b1, gamma, beta,
                                 W2, b2, out + 128, out, logits, done);
}

// Round 10
// 110.551 us; speedup vs baseline: 1.1013x; 1.1013x over previous
//
#include <hip/hip_runtime.h>
#include <math.h>

#define Bn 64
#define QLn 40
#define ALn 60
#define Dn 300
#define KS 640       /* stored row width: [hi(320) | lo(320)] */
#define NQ 1024      /* Q job cols: 768 sm-conv | 256 attnW2 */
#define NA 1536      /* A job cols: 768 sm-conv | 768 ctx-conv */

typedef __attribute__((ext_vector_type(8))) short bf16x8;
typedef __attribute__((ext_vector_type(4))) float f32x4;

__device__ __forceinline__ float bf2f(unsigned short s) {
  return __uint_as_float(((unsigned)s) << 16);
}
__device__ __forceinline__ short f2bf(float f) {
  unsigned u = __float_as_uint(f);
  unsigned r = (u + 0x7FFFu + ((u >> 16) & 1u)) >> 16;
  return (short)r;
}
__device__ __forceinline__ float2 bf2x2(unsigned int p) {
  return make_float2(__uint_as_float(p << 16), __uint_as_float(p & 0xFFFF0000u));
}

// ============ fused prep ============
// bid [0,1600): gather -> split-bf16 [hi|lo] + row norms
// bid [1600,1800): BT transpose (coalesced, LDS tile)
// bid [1800,2057): Wcat = [ctxfcW | ctxfcW@attnW0] + bvec
// bid 2057: zero num/den/logits/done
__global__ __launch_bounds__(256) void k_prep(
    const int* __restrict__ qIdx, const int* __restrict__ aIdx,
    const float* __restrict__ emb,
    const float* __restrict__ smW, const float* __restrict__ ctxW,
    const float* __restrict__ attnW, const float* __restrict__ ctxfcW,
    const float* __restrict__ ctxfcb, const float* __restrict__ attnb,
    short* __restrict__ Ae1, short* __restrict__ Ae2,
    float* __restrict__ nq, float* __restrict__ na,
    short* __restrict__ BTall, float* __restrict__ Wcat, float* __restrict__ bvec,
    float* __restrict__ numb, float* __restrict__ denb,
    float* __restrict__ logits, int* __restrict__ done) {
  __shared__ float lds[4160];
  int bid = blockIdx.x, tid = threadIdx.x;
  int w = tid >> 6, lane = tid & 63;
  if (bid < 1600) {
    int row = bid * 4 + w;
    const int* idxp; short* Ae; float* nrm; int r;
    if (row < 2560) { idxp = qIdx; Ae = Ae1; nrm = nq; r = row; }
    else { idxp = aIdx; Ae = Ae2; nrm = na; r = row - 2560; }
    int tok = idxp[r];
    const float4* src = (const float4*)(emb + (size_t)tok * Dn);
    short* d = Ae + (size_t)r * KS;
    float ssq = 0.f;
    for (int i = lane; i < 80; i += 64) {
      float4 v = (i < 75) ? src[i] : make_float4(0.f, 0.f, 0.f, 0.f);
      ssq += v.x * v.x + v.y * v.y + v.z * v.z + v.w * v.w;
      short4 h4, l4v;
      h4.x = f2bf(v.x); l4v.x = f2bf(v.x - bf2f((unsigned short)h4.x));
      h4.y = f2bf(v.y); l4v.y = f2bf(v.y - bf2f((unsigned short)h4.y));
      h4.z = f2bf(v.z); l4v.z = f2bf(v.z - bf2f((unsigned short)h4.z));
      h4.w = f2bf(v.w); l4v.w = f2bf(v.w - bf2f((unsigned short)h4.w));
      *(short4*)&d[i * 4] = h4;
      *(short4*)&d[320 + i * 4] = l4v;
    }
    #pragma unroll
    for (int o = 32; o; o >>= 1) ssq += __shfl_down(ssq, o, 64);
    if (lane == 0) nrm[r] = sqrtf(ssq);
  } else if (bid < 1800) {
    int tb = bid - 1600;
    int kt = tb % 5, nt = tb / 5;
    int n0 = nt * 64;
    const float* src; int cb;
    if (n0 < 768)       { src = smW + (n0 >> 8) * 76800; cb = n0 & 255; }
    else if (n0 < 1024) { src = attnW + 65536;           cb = n0 - 768; }
    else if (n0 < 1792) { int m = n0 - 1024; src = smW + (m >> 8) * 76800; cb = m & 255; }
    else                { int m = n0 - 1792; src = ctxW + (m >> 8) * 76800; cb = m & 255; }
    float* tile = lds;   // [64][65]
    int nn = tid & 63;
    #pragma unroll
    for (int it = 0; it < 16; ++it) {
      int kl = it * 4 + w;
      int k = kt * 64 + kl;
      tile[kl * 65 + nn] = (k < 300) ? src[(size_t)k * 256 + cb + nn] : 0.f;
    }
    __syncthreads();
    #pragma unroll
    for (int it = 0; it < 16; ++it) {
      int nloc = it * 4 + w;
      int kl = tid & 63;
      float v = tile[kl * 65 + nloc];
      int n = n0 + nloc, k = kt * 64 + kl;
      short hi = f2bf(v), lo = f2bf(v - bf2f((unsigned short)hi));
      BTall[(size_t)n * KS + k] = hi;
      BTall[(size_t)n * KS + 320 + k] = lo;
    }
  } else if (bid < 2057) {
    int k = bid - 1800;            // 0..256
    float* rowv = lds;
    int j = tid;
    rowv[j] = (k < 256) ? ctxfcW[(size_t)k * 256 + j] : ctxfcb[j];
    __syncthreads();
    float a0 = 0.f, a1 = 0.f, a2 = 0.f, a3 = 0.f;
    for (int m = 0; m < 256; m += 4) {
      a0 += rowv[m]     * attnW[(size_t)m * 256 + j];
      a1 += rowv[m + 1] * attnW[(size_t)(m + 1) * 256 + j];
      a2 += rowv[m + 2] * attnW[(size_t)(m + 2) * 256 + j];
      a3 += rowv[m + 3] * attnW[(size_t)(m + 3) * 256 + j];
    }
    float acc = (a0 + a1) + (a2 + a3);
    if (k < 256) {
      Wcat[(size_t)k * 512 + j] = rowv[j];
      Wcat[(size_t)k * 512 + 256 + j] = acc;
    } else {
      bvec[j] = ctxfcb[j];
      bvec[256 + j] = acc + attnb[j];
    }
  } else {
    for (int i = tid; i < Bn * 256; i += 256) numb[i] = 0.f;
    if (tid < Bn) denb[tid] = 0.f;
    if (tid < 2 * Bn) logits[tid] = 0.f;
    if (tid == 0) *done = 0;
  }
}

// ============ split mega MFMA GEMM (bf16 out) + MFMA cosine ============
__device__ __forceinline__ void gl2lds16(const short* g, short* l) {
  __builtin_amdgcn_global_load_lds(
      (const __attribute__((address_space(1))) unsigned int*)g,
      (__attribute__((address_space(3))) unsigned int*)l, 16, 0, 0);
}

__global__ __launch_bounds__(256) void k_mega(
    const short* __restrict__ Ae1, const short* __restrict__ Ae2,
    const short* __restrict__ BTall, short* __restrict__ ZQb, short* __restrict__ ZAb,
    const float* __restrict__ nq, const float* __restrict__ na,
    float* __restrict__ cosb) {
  __shared__ __align__(16) short As[128 * 32];
  __shared__ __align__(16) short Bs[128 * 32];
  int tid = threadIdx.x;
  int wid = tid >> 6, lane = tid & 63;
  int l15 = lane & 15, l4 = lane >> 4;
  int bid = blockIdx.x;
  int lin = (bid & 7) * 73 + (bid >> 3);   // bijective XCD swizzle, 584 = 8 x 73

  if (lin < 520) {
    const short *A, *BT; short* C; int bx, by, ldc;
    if (lin < 160) {            // Q job: 20 x 8 tiles
      int chunk = lin >> 4, ww = lin & 15;
      by = ww >> 1; bx = chunk * 2 + (ww & 1);
      A = Ae1; BT = BTall; C = ZQb; ldc = NQ;
    } else {                    // A job: 30 x 12 tiles
      int l2 = lin - 160;
      int chunk = l2 / 24, ww = l2 % 24;
      by = ww >> 1; bx = chunk * 2 + (ww & 1);
      A = Ae2; BT = BTall + (size_t)1024 * KS; C = ZAb; ldc = NA;
    }
    int rowBase = bx * 128, colBase = by * 128;
    int mw = wid * 32;

    f32x4 acc[2][8];
    #pragma unroll
    for (int i = 0; i < 2; ++i)
      #pragma unroll
      for (int j = 0; j < 8; ++j) acc[i][j] = (f32x4){0.f, 0.f, 0.f, 0.f};

    int rowA0 = mw + l15, rowA1 = mw + 16 + l15;
    int sA0 = (l4 ^ ((rowA0 >> 1) & 3)) << 3;
    int sA1 = (l4 ^ ((rowA1 >> 1) & 3)) << 3;

    #pragma unroll 1
    for (int g = 0; g < 3; ++g) {
      int aoff = (g == 1) ? 320 : 0;
      int boff = (g == 2) ? 320 : 0;
      #pragma unroll 1
      for (int ks = 0; ks < 10; ++ks) {
        int ka0 = aoff + ks * 32, kb0 = boff + ks * 32;
        #pragma unroll
        for (int j = 0; j < 2; ++j) {
          int idx = tid + j * 256;
          int r = idx >> 2, s = idx & 3;
          int sl = s ^ ((r >> 1) & 3);
          int chunkStart = j * 256 + wid * 64;
          gl2lds16(A + (size_t)(rowBase + r) * KS + ka0 + (sl << 3), &As[chunkStart * 8]);
          gl2lds16(BT + (size_t)(colBase + r) * KS + kb0 + (sl << 3), &Bs[chunkStart * 8]);
        }
        __syncthreads();
        bf16x8 a0 = *reinterpret_cast<const bf16x8*>(&As[rowA0 * 32 + sA0]);
        bf16x8 a1 = *reinterpret_cast<const bf16x8*>(&As[rowA1 * 32 + sA1]);
        #pragma unroll
        for (int nj = 0; nj < 8; ++nj) {
          int rb = nj * 16 + l15;
          bf16x8 bf = *reinterpret_cast<const bf16x8*>(&Bs[rb * 32 + ((l4 ^ ((rb >> 1) & 3)) << 3)]);
          acc[0][nj] = __builtin_amdgcn_mfma_f32_16x16x32_bf16(a0, bf, acc[0][nj], 0, 0, 0);
          acc[1][nj] = __builtin_amdgcn_mfma_f32_16x16x32_bf16(a1, bf, acc[1][nj], 0, 0, 0);
        }
        __syncthreads();
      }
    }
    #pragma unroll
    for (int mi = 0; mi < 2; ++mi) {
      int row0 = rowBase + mw + mi * 16 + l4 * 4;
      #pragma unroll
      for (int nj = 0; nj < 8; ++nj) {
        int col = colBase + nj * 16 + l15;
        #pragma unroll
        for (int r = 0; r < 4; ++r)
          C[(size_t)(row0 + r) * ldc + col] = f2bf(acc[mi][nj][r]);
      }
    }
  } else {
    // ---- cosine job: per-b 64x64 MFMA tile ----
    int b = lin - 520;
    int rowBase = b * 40, colBase = b * 60;
    f32x4 cacc[4];
    #pragma unroll
    for (int nj = 0; nj < 4; ++nj) cacc[nj] = (f32x4){0.f, 0.f, 0.f, 0.f};
    int rowA = (wid << 4) + l15;
    int sA = (l4 ^ ((rowA >> 1) & 3)) << 3;

    #pragma unroll 1
    for (int g = 0; g < 3; ++g) {
      int aoff = (g == 1) ? 320 : 0;
      int boff = (g == 2) ? 320 : 0;
      #pragma unroll 1
      for (int ks = 0; ks < 10; ++ks) {
        int ka0 = aoff + ks * 32, kb0 = boff + ks * 32;
        int r = tid >> 2, s = tid & 3;
        int sl = s ^ ((r >> 1) & 3);
        int chunkStart = wid * 64;
        int gr = rowBase + r; if (gr > 2559) gr = 2559;
        int gc = colBase + r; if (gc > 3839) gc = 3839;
        gl2lds16(Ae1 + (size_t)gr * KS + ka0 + (sl << 3), &As[chunkStart * 8]);
        gl2lds16(Ae2 + (size_t)gc * KS + kb0 + (sl << 3), &Bs[chunkStart * 8]);
        __syncthreads();
        bf16x8 a0 = *reinterpret_cast<const bf16x8*>(&As[rowA * 32 + sA]);
        #pragma unroll
        for (int nj = 0; nj < 4; ++nj) {
          int rb = (nj << 4) + l15;
          bf16x8 bf = *reinterpret_cast<const bf16x8*>(&Bs[rb * 32 + ((l4 ^ ((rb >> 1) & 3)) << 3)]);
          cacc[nj] = __builtin_amdgcn_mfma_f32_16x16x32_bf16(a0, bf, cacc[nj], 0, 0, 0);
        }
        __syncthreads();
      }
    }
    int q0 = (wid << 4) + l4 * 4;
    #pragma unroll
    for (int nj = 0; nj < 4; ++nj) {
      int a = (nj << 4) + l15;
      if (a >= ALn) continue;
      float nav = na[colBase + a];
      #pragma unroll
      for (int r = 0; r < 4; ++r) {
        int qq = q0 + r;
        if (qq < QLn) {
          float den = fmaxf(nq[rowBase + qq] * nav, 1e-6f);
          cosb[(size_t)(rowBase + qq) * ALn + a] = cacc[nj][r] / den;
        }
      }
    }
  }
}

// ============ pools (bf16 in, short2 col-pair loads, t-split across thread halves) ============
// bid [0,128): sm pool, 1 sentence per block
// bid [128,448): ctx pool, (b, qg of 8 q's) per block
__global__ __launch_bounds__(256) void k_pool(
    const short* __restrict__ ZQb, const short* __restrict__ ZAb,
    const float* __restrict__ convb, const float* __restrict__ cosb,
    const float* __restrict__ ctxb,
    float* __restrict__ pooled_part, float* __restrict__ pctx_part) {
  __shared__ float cl[8][ALn];
  int bid = blockIdx.x, tid = threadIdx.x;
  int cp = tid & 127, th = tid >> 7;
  int c2 = cp * 2;
  if (bid < 128) {
    int s = bid;
    const short* zb; int L, ld;
    if (s < Bn) { zb = ZQb + (size_t)s * QLn * NQ; L = QLn; ld = NQ; }
    else        { zb = ZAb + (size_t)(s - Bn) * ALn * NA; L = ALn; ld = NA; }
    int P = L - 2;
    int t0 = th * (P >> 1), t1 = (th ? P : (P >> 1));
    float b0 = convb[c2], b1 = convb[c2 + 1];
    float m0 = 0.f, m1 = 0.f;
    for (int t = t0; t < t1; ++t) {
      float2 v0 = bf2x2(*(const unsigned int*)&zb[t * ld + c2]);
      float2 v1 = bf2x2(*(const unsigned int*)&zb[(t + 1) * ld + 256 + c2]);
      float2 v2 = bf2x2(*(const unsigned int*)&zb[(t + 2) * ld + 512 + c2]);
      m0 = fmaxf(m0, b0 + v0.x + v1.x + v2.x);
      m1 = fmaxf(m1, b1 + v0.y + v1.y + v2.y);
    }
    float* dst = pooled_part + ((size_t)th * 128 + s) * 256 + c2;
    dst[0] = m0; dst[1] = m1;
  } else {
    int g = bid - 128;
    int b = g / 5, q0 = (g % 5) * 8;
    int rq = b * QLn + q0;
    for (int i = tid; i < 8 * ALn; i += 256)
      cl[i / ALn][i % ALn] = cosb[(size_t)(rq + i / ALn) * ALn + (i % ALn)];
    __syncthreads();
    const short* zb = ZAb + (size_t)b * ALn * NA + 768;
    float b0 = ctxb[c2], b1 = ctxb[c2 + 1];
    float m[8][2];
    #pragma unroll
    for (int rr = 0; rr < 8; ++rr) { m[rr][0] = 0.f; m[rr][1] = 0.f; }
    int t0 = th * 29;
    for (int t = t0; t < t0 + 29; ++t) {
      float2 v0 = bf2x2(*(const unsigned int*)&zb[t * NA + c2]);
      float2 v1 = bf2x2(*(const unsigned int*)&zb[(t + 1) * NA + 256 + c2]);
      float2 v2 = bf2x2(*(const unsigned int*)&zb[(t + 2) * NA + 512 + c2]);
      #pragma unroll
      for (int rr = 0; rr < 8; ++rr) {
        float c0 = cl[rr][t], c1 = cl[rr][t + 1], c2v = cl[rr][t + 2];
        m[rr][0] = fmaxf(m[rr][0], b0 + c0 * v0.x + c1 * v1.x + c2v * v2.x);
        m[rr][1] = fmaxf(m[rr][1], b1 + c0 * v0.y + c1 * v1.y + c2v * v2.y);
      }
    }
    #pragma unroll
    for (int rr = 0; rr < 8; ++rr) {
      float* dst = pctx_part + ((size_t)th * 2560 + rq + rr) * 256 + c2;
      dst[0] = m[rr][0]; dst[1] = m[rr][1];
    }
  }
}

// ============ fused: fc (32 blocks) | ctx-fc+attn-MLP+score+num/den (320 blocks) ============
__global__ __launch_bounds__(256) void k_fcattn(
    const float* __restrict__ pooled_part, const float* __restrict__ smfcW,
    const float* __restrict__ smfcb, const float* __restrict__ pctx_part,
    const short* __restrict__ ZQb, const float* __restrict__ Wcat,
    const float* __restrict__ bvec, const float* __restrict__ probW,
    float* __restrict__ feat_comb, float* __restrict__ numb, float* __restrict__ denb) {
  __shared__ float lds[10304];   // xin[2048] | wt[8192] | sred[64]
  int bid = blockIdx.x, j = threadIdx.x;
  if (bid < 32) {
    float* xin = lds;            // [256][4]
    float* wt  = lds + 1024;     // [32][256]
    int r0 = bid * 4;
    #pragma unroll
    for (int rr = 0; rr < 4; ++rr)
      xin[j * 4 + rr] = fmaxf(pooled_part[(size_t)(r0 + rr) * 256 + j],
                              pooled_part[(size_t)(128 + r0 + rr) * 256 + j]);
    float acc[4];
    #pragma unroll
    for (int rr = 0; rr < 4; ++rr) acc[rr] = smfcb[j];
    for (int ph = 0; ph < 8; ++ph) {
      const float4* src = (const float4*)(smfcW + (size_t)ph * 32 * 256);
      float4* dst = (float4*)wt;
      #pragma unroll
      for (int i = 0; i < 8; ++i) dst[i * 256 + j] = src[i * 256 + j];
      __syncthreads();
      #pragma unroll
      for (int kk = 0; kk < 32; ++kk) {
        float4 x = *reinterpret_cast<const float4*>(&xin[(ph * 32 + kk) * 4]);
        float wv = wt[kk * 256 + j];
        acc[0] += x.x * wv; acc[1] += x.y * wv; acc[2] += x.z * wv; acc[3] += x.w * wv;
      }
      __syncthreads();
    }
    #pragma unroll
    for (int rr = 0; rr < 4; ++rr) {
      int row = r0 + rr;
      feat_comb[(size_t)(row & 63) * 512 + ((row >> 6) * 256) + j] = acc[rr];
    }
  } else {
    float* xin  = lds;           // [256][8]
    float* wt   = lds + 2048;    // [16][512]
    float* sred = lds + 10240;   // [8][4]
    int g = bid - 32;
    int b = g / 5, q0 = (g % 5) * 8;
    int rq = b * QLn + q0;
    #pragma unroll
    for (int rr = 0; rr < 8; ++rr)
      xin[j * 8 + rr] = fmaxf(pctx_part[(size_t)(rq + rr) * 256 + j],
                              pctx_part[(size_t)(2560 + rq + rr) * 256 + j]);
    float hf[8], hh[8];
    float bf0 = bvec[j], bh0 = bvec[256 + j];
    #pragma unroll
    for (int rr = 0; rr < 8; ++rr) {
      hf[rr] = bf0;
      hh[rr] = bh0 + bf2f((unsigned short)ZQb[(size_t)(rq + rr) * NQ + 768 + j]);
    }
    for (int ph = 0; ph < 16; ++ph) {
      const float4* src = (const float4*)(Wcat + (size_t)ph * 16 * 512);
      float4* dst = (float4*)wt;
      #pragma unroll
      for (int i = 0; i < 8; ++i) dst[i * 256 + j] = src[i * 256 + j];
      __syncthreads();
      #pragma unroll
      for (int kk = 0; kk < 16; ++kk) {
        int k = ph * 16 + kk;
        float4 x0 = *reinterpret_cast<const float4*>(&xin[k * 8]);
        float4 x1 = *reinterpret_cast<const float4*>(&xin[k * 8 + 4]);
        float w0 = wt[kk * 512 + j], w1 = wt[kk * 512 + 256 + j];
        hf[0] += x0.x * w0; hf[1] += x0.y * w0; hf[2] += x0.z * w0; hf[3] += x0.w * w0;
        hf[4] += x1.x * w0; hf[5] += x1.y * w0; hf[6] += x1.z * w0; hf[7] += x1.w * w0;
        hh[0] += x0.x * w1; hh[1] += x0.y * w1; hh[2] += x0.z * w1; hh[3] += x0.w * w1;
        hh[4] += x1.x * w1; hh[5] += x1.y * w1; hh[6] += x1.z * w1; hh[7] += x1.w * w1;
      }
      __syncthreads();
    }
    float pw = probW[j];
    int lane = j & 63, wv = j >> 6;
    #pragma unroll
    for (int rr = 0; rr < 8; ++rr) {
      float s = tanhf(hh[rr]) * pw;
      #pragma unroll
      for (int off = 32; off; off >>= 1) s += __shfl_down(s, off, 64);
      if (lane == 0) sred[rr * 4 + wv] = s;
    }
    __syncthreads();
    float e[8], esum = 0.f, acc3 = 0.f;
    #pragma unroll
    for (int rr = 0; rr < 8; ++rr) {
      float s = sred[rr * 4] + sred[rr * 4 + 1] + sred[rr * 4 + 2] + sred[rr * 4 + 3];
      e[rr] = __expf(s);       // |s| <= sum|probW| ~ 4: safe without max-sub
      esum += e[rr];
      acc3 += e[rr] * hf[rr];
    }
    atomicAdd(&numb[(size_t)b * 256 + j], acc3);
    if (j == 0) atomicAdd(&denb[b], esum);
  }
}

// ============ fused W1(+feature3 via num/den) + BN + tanh + head (last block) ============
__global__ __launch_bounds__(256) void k_w1bn(
    const float* __restrict__ feat_comb, const float* __restrict__ numb,
    const float* __restrict__ denb, const float* __restrict__ W1,
    const float* __restrict__ b1, const float* __restrict__ gamma,
    const float* __restrict__ beta, const float* __restrict__ W2,
    const float* __restrict__ b2, float* __restrict__ feat_out,
    float* __restrict__ preds, float* __restrict__ logits, int* __restrict__ done) {
  int j0 = blockIdx.x * 8;
  int tid = threadIdx.x;
  __shared__ float wl[768][12];
  __shared__ float hb[64][8];
  __shared__ int lastflag;
  for (int it = 0; it < 24; ++it) {
    int idx = tid + it * 256;
    int k = idx >> 3, jj = idx & 7;
    wl[k][jj] = W1[(size_t)k * 512 + j0 + jj];
  }
  __syncthreads();
  int n = tid >> 2, p = tid & 3;
  float acc1[8] = {0.f, 0.f, 0.f, 0.f, 0.f, 0.f, 0.f, 0.f};
  float acc2[8] = {0.f, 0.f, 0.f, 0.f, 0.f, 0.f, 0.f, 0.f};
  const float* frow = feat_comb + (size_t)n * 512 + p;
  for (int i = 0; i < 128; ++i) {
    float v = frow[i * 4];
    int k = p + i * 4;
    float4 w0 = *reinterpret_cast<const float4*>(&wl[k][0]);
    float4 w1v = *reinterpret_cast<const float4*>(&wl[k][4]);
    acc1[0] += v * w0.x; acc1[1] += v * w0.y; acc1[2] += v * w0.z; acc1[3] += v * w0.w;
    acc1[4] += v * w1v.x; acc1[5] += v * w1v.y; acc1[6] += v * w1v.z; acc1[7] += v * w1v.w;
  }
  const float* nrow = numb + (size_t)n * 256 + p;
  for (int i = 0; i < 64; ++i) {
    float v = nrow[i * 4];
    int k = 512 + p + i * 4;
    float4 w0 = *reinterpret_cast<const float4*>(&wl[k][0]);
    float4 w1v = *reinterpret_cast<const float4*>(&wl[k][4]);
    acc2[0] += v * w0.x; acc2[1] += v * w0.y; acc2[2] += v * w0.z; acc2[3] += v * w0.w;
    acc2[4] += v * w1v.x; acc2[5] += v * w1v.y; acc2[6] += v * w1v.z; acc2[7] += v * w1v.w;
  }
  #pragma unroll
  for (int jj = 0; jj < 8; ++jj) {
    acc1[jj] += __shfl_xor(acc1[jj], 1, 64);
    acc1[jj] += __shfl_xor(acc1[jj], 2, 64);
    acc2[jj] += __shfl_xor(acc2[jj], 1, 64);
    acc2[jj] += __shfl_xor(acc2[jj], 2, 64);
  }
  if (p == 0) {
    float rden = 1.f / denb[n];
    #pragma unroll
    for (int jj = 0; jj < 8; ++jj) hb[n][jj] = acc1[jj] + rden * acc2[jj] + b1[j0 + jj];
  }
  __syncthreads();
  if (tid < 64) {
    float l0p = 0.f, l1p = 0.f;
    #pragma unroll
    for (int jj = 0; jj < 8; ++jj) {
      float v = hb[tid][jj];
      float s = v;
      #pragma unroll
      for (int off = 32; off; off >>= 1) s += __shfl_xor(s, off, 64);
      float mu = s * (1.f / 64.f);
      float d = v - mu;
      float q2 = d * d;
      #pragma unroll
      for (int off = 32; off; off >>= 1) q2 += __shfl_xor(q2, off, 64);
      float var = q2 * (1.f / 64.f);
      float fo = tanhf(d * rsqrtf(var + 1e-5f) * gamma[j0 + jj] + beta[j0 + jj]);
      feat_out[(size_t)tid * 512 + j0 + jj] = fo;
      l0p += fo * W2[(j0 + jj) * 2 + 0];
      l1p += fo * W2[(j0 + jj) * 2 + 1];
    }
    atomicAdd(&logits[tid * 2 + 0], l0p);
    atomicAdd(&logits[tid * 2 + 1], l1p);
  }
  __threadfence();
  __syncthreads();
  if (tid == 0) lastflag = (atomicAdd(done, 1) == gridDim.x - 1) ? 1 : 0;
  __syncthreads();
  if (lastflag && tid < 64) {
    __threadfence();
    float l0 = atomicAdd(&logits[tid * 2 + 0], 0.f) + b2[0];
    float l1 = atomicAdd(&logits[tid * 2 + 1], 0.f) + b2[1];
    float mx = fmaxf(l0, l1);
    float lse = mx + logf(__expf(l0 - mx) + __expf(l1 - mx));
    preds[tid * 2 + 0] = l0 - lse;
    preds[tid * 2 + 1] = l1 - lse;
  }
}

extern "C" void kernel_launch(void* const* d_in, const int* in_sizes, int n_in,
                              void* d_out, int out_size, void* d_ws, size_t ws_size,
                              hipStream_t stream) {
  (void)in_sizes; (void)n_in; (void)out_size; (void)ws_size;
  const int*   question  = (const int*)d_in[0];
  const int*   answer    = (const int*)d_in[1];
  const float* embedding = (const float*)d_in[3];
  const float* sm_convW  = (const float*)d_in[4];
  const float* sm_convb  = (const float*)d_in[5];
  const float* sm_fcW    = (const float*)d_in[6];
  const float* sm_fcb    = (const float*)d_in[7];
  const float* ctx_convW = (const float*)d_in[8];
  const float* ctx_convb = (const float*)d_in[9];
  const float* ctx_fcW   = (const float*)d_in[10];
  const float* ctx_fcb   = (const float*)d_in[11];
  const float* attnW     = (const float*)d_in[12];
  const float* attnb     = (const float*)d_in[13];
  const float* probW     = (const float*)d_in[14];
  const float* W1        = (const float*)d_in[15];
  const float* b1        = (const float*)d_in[16];
  const float* gamma     = (const float*)d_in[17];
  const float* beta      = (const float*)d_in[18];
  const float* W2        = (const float*)d_in[19];
  const float* b2        = (const float*)d_in[20];

  float* out = (float*)d_out;   // [0:128) preds, [128:) feat_out 64x512
  char* base = (char*)d_ws;
  size_t off = 0;
  auto alloc = [&](size_t bytes) { char* p = base + off; off += (bytes + 255) & ~(size_t)255; return p; };

  short* Ae1   = (short*)alloc(2560ull * KS * 2);      // 3.28 MB
  short* Ae2   = (short*)alloc(3840ull * KS * 2);      // 4.92 MB
  short* BTall = (short*)alloc(2560ull * KS * 2);      // 3.28 MB; dead after k_mega
  short* ZQb   = (short*)alloc(2560ull * NQ * 2);      // 5.24 MB (bf16)
  short* ZAb   = (short*)alloc(3840ull * NA * 2);      // 11.8 MB (bf16)
  float* nq    = (float*)alloc(2560 * 4);
  float* na    = (float*)alloc(3840 * 4);
  float* cosb  = (float*)alloc(2560ull * ALn * 4);
  float* Wcat  = (float*)alloc(256ull * 512 * 4);
  float* bvec  = (float*)alloc(512 * 4);
  float* pctx_part = (float*)alloc(2ull * 2560 * 256 * 4);   // 5.24 MB
  float* feat_comb = (float*)alloc(64ull * 512 * 4);
  float* numb   = (float*)alloc(64ull * 256 * 4);
  float* denb   = (float*)alloc(64 * 4);
  float* logits = (float*)alloc(128 * 4);
  int*   done   = (int*)alloc(256);
  float* pooled_part = (float*)BTall;                  // overlay (dead after k_mega)

  // 1. prep: gather+norms | BT-transpose | Wcat | zero-accumulators (2058 blocks)
  k_prep<<<2058, 256, 0, stream>>>(question, answer, embedding, sm_convW, ctx_convW,
                                   attnW, ctx_fcW, ctx_fcb, attnb,
                                   Ae1, Ae2, nq, na, BTall, Wcat, bvec,
                                   numb, denb, logits, done);
  // 2. split mega GEMM (bf16 out) + MFMA cosine (584 blocks)
  k_mega<<<584, 256, 0, stream>>>(Ae1, Ae2, BTall, ZQb, ZAb, nq, na, cosb);
  // 3. pools: sm (128) | ctx (320) — short2 col-pair loads, t-split in-block
  k_pool<<<448, 256, 0, stream>>>(ZQb, ZAb, sm_convb, cosb, ctx_convb,
                                  pooled_part, pctx_part);
  // 4. fc | ctx-fc + attn + score + softmax num/den (352 blocks)
  k_fcattn<<<352, 256, 0, stream>>>(pooled_part, sm_fcW, sm_fcb, pctx_part,
                                    ZQb, Wcat, bvec, probW,
                                    feat_comb, numb, denb);
  // 5. W1 + feature3 + BN + tanh + head (64 blocks, last-block log_softmax)
  k_w1bn<<<64, 256, 0, stream>>>(feat_comb, numb, denb, W1, b1, gamma, beta,
                                 W2, b2, out + 128, out, logits, done);
}

// Round 11
// 98.458 us; speedup vs baseline: 1.2365x; 1.1228x over previous
//
#include <hip/hip_runtime.h>
#include <math.h>

#define Bn 64
#define QLn 40
#define ALn 60
#define Dn 300
#define KS 320       /* fp16 row width (300 + pad) */
#define NQ 1024      /* Q job cols: 768 sm-conv | 256 attnW2 */
#define NA 1536      /* A job cols: 768 sm-conv | 768 ctx-conv */

typedef _Float16 f16x8 __attribute__((ext_vector_type(8)));
typedef __attribute__((ext_vector_type(4))) float f32x4;

__device__ __forceinline__ short f2h(float f) {
  _Float16 h = (_Float16)f;
  return __builtin_bit_cast(short, h);
}
__device__ __forceinline__ float h2f(short s) {
  return (float)__builtin_bit_cast(_Float16, s);
}
__device__ __forceinline__ float2 h2x2(unsigned int p) {
  union { unsigned int u; _Float16 h[2]; } cv; cv.u = p;
  return make_float2((float)cv.h[0], (float)cv.h[1]);
}

// ============ fused prep ============
// bid [0,1600): gather -> fp16 rows + fp32 row norms
// bid [1600,1800): BT transpose (coalesced, LDS tile) -> fp16
// bid [1800,2057): Wcat = [ctxfcW | ctxfcW@attnW0] + bvec (fp32)
// bid 2057: zero num/den/logits/done
__global__ __launch_bounds__(256) void k_prep(
    const int* __restrict__ qIdx, const int* __restrict__ aIdx,
    const float* __restrict__ emb,
    const float* __restrict__ smW, const float* __restrict__ ctxW,
    const float* __restrict__ attnW, const float* __restrict__ ctxfcW,
    const float* __restrict__ ctxfcb, const float* __restrict__ attnb,
    short* __restrict__ Ae1, short* __restrict__ Ae2,
    float* __restrict__ nq, float* __restrict__ na,
    short* __restrict__ BTall, float* __restrict__ Wcat, float* __restrict__ bvec,
    float* __restrict__ numb, float* __restrict__ denb,
    float* __restrict__ logits, int* __restrict__ done) {
  __shared__ float lds[4160];
  int bid = blockIdx.x, tid = threadIdx.x;
  int w = tid >> 6, lane = tid & 63;
  if (bid < 1600) {
    int row = bid * 4 + w;
    const int* idxp; short* Ae; float* nrm; int r;
    if (row < 2560) { idxp = qIdx; Ae = Ae1; nrm = nq; r = row; }
    else { idxp = aIdx; Ae = Ae2; nrm = na; r = row - 2560; }
    int tok = idxp[r];
    const float4* src = (const float4*)(emb + (size_t)tok * Dn);
    short* d = Ae + (size_t)r * KS;
    float ssq = 0.f;
    for (int i = lane; i < 80; i += 64) {
      float4 v = (i < 75) ? src[i] : make_float4(0.f, 0.f, 0.f, 0.f);
      ssq += v.x * v.x + v.y * v.y + v.z * v.z + v.w * v.w;
      short4 h4;
      h4.x = f2h(v.x); h4.y = f2h(v.y); h4.z = f2h(v.z); h4.w = f2h(v.w);
      *(short4*)&d[i * 4] = h4;
    }
    #pragma unroll
    for (int o = 32; o; o >>= 1) ssq += __shfl_down(ssq, o, 64);
    if (lane == 0) nrm[r] = sqrtf(ssq);
  } else if (bid < 1800) {
    int tb = bid - 1600;
    int kt = tb % 5, nt = tb / 5;
    int n0 = nt * 64;
    const float* src; int cb;
    if (n0 < 768)       { src = smW + (n0 >> 8) * 76800; cb = n0 & 255; }
    else if (n0 < 1024) { src = attnW + 65536;           cb = n0 - 768; }
    else if (n0 < 1792) { int m = n0 - 1024; src = smW + (m >> 8) * 76800; cb = m & 255; }
    else                { int m = n0 - 1792; src = ctxW + (m >> 8) * 76800; cb = m & 255; }
    float* tile = lds;   // [64][65]
    int nn = tid & 63;
    #pragma unroll
    for (int it = 0; it < 16; ++it) {
      int kl = it * 4 + w;
      int k = kt * 64 + kl;
      tile[kl * 65 + nn] = (k < 300) ? src[(size_t)k * 256 + cb + nn] : 0.f;
    }
    __syncthreads();
    #pragma unroll
    for (int it = 0; it < 16; ++it) {
      int nloc = it * 4 + w;
      int kl = tid & 63;
      float v = tile[kl * 65 + nloc];
      int n = n0 + nloc, k = kt * 64 + kl;
      BTall[(size_t)n * KS + k] = f2h(v);
    }
  } else if (bid < 2057) {
    int k = bid - 1800;            // 0..256
    float* rowv = lds;
    int j = tid;
    rowv[j] = (k < 256) ? ctxfcW[(size_t)k * 256 + j] : ctxfcb[j];
    __syncthreads();
    float a0 = 0.f, a1 = 0.f, a2 = 0.f, a3 = 0.f;
    for (int m = 0; m < 256; m += 4) {
      a0 += rowv[m]     * attnW[(size_t)m * 256 + j];
      a1 += rowv[m + 1] * attnW[(size_t)(m + 1) * 256 + j];
      a2 += rowv[m + 2] * attnW[(size_t)(m + 2) * 256 + j];
      a3 += rowv[m + 3] * attnW[(size_t)(m + 3) * 256 + j];
    }
    float acc = (a0 + a1) + (a2 + a3);
    if (k < 256) {
      Wcat[(size_t)k * 512 + j] = rowv[j];
      Wcat[(size_t)k * 512 + 256 + j] = acc;
    } else {
      bvec[j] = ctxfcb[j];
      bvec[256 + j] = acc + attnb[j];
    }
  } else {
    for (int i = tid; i < Bn * 256; i += 256) numb[i] = 0.f;
    if (tid < Bn) denb[tid] = 0.f;
    if (tid < 2 * Bn) logits[tid] = 0.f;
    if (tid == 0) *done = 0;
  }
}

// ============ split mega MFMA GEMM (fp16 in/out) + MFMA cosine ============
__device__ __forceinline__ void gl2lds16(const short* g, short* l) {
  __builtin_amdgcn_global_load_lds(
      (const __attribute__((address_space(1))) unsigned int*)g,
      (__attribute__((address_space(3))) unsigned int*)l, 16, 0, 0);
}

__global__ __launch_bounds__(256) void k_mega(
    const short* __restrict__ Ae1, const short* __restrict__ Ae2,
    const short* __restrict__ BTall, short* __restrict__ ZQh, short* __restrict__ ZAh,
    const float* __restrict__ nq, const float* __restrict__ na,
    float* __restrict__ cosb) {
  __shared__ __align__(16) short As[128 * 32];
  __shared__ __align__(16) short Bs[128 * 32];
  int tid = threadIdx.x;
  int wid = tid >> 6, lane = tid & 63;
  int l15 = lane & 15, l4 = lane >> 4;
  int bid = blockIdx.x;
  int lin = (bid & 7) * 73 + (bid >> 3);   // bijective XCD swizzle, 584 = 8 x 73

  if (lin < 520) {
    const short *A, *BT; short* C; int bx, by, ldc;
    if (lin < 160) {            // Q job: 20 x 8 tiles
      int chunk = lin >> 4, ww = lin & 15;
      by = ww >> 1; bx = chunk * 2 + (ww & 1);
      A = Ae1; BT = BTall; C = ZQh; ldc = NQ;
    } else {                    // A job: 30 x 12 tiles
      int l2 = lin - 160;
      int chunk = l2 / 24, ww = l2 % 24;
      by = ww >> 1; bx = chunk * 2 + (ww & 1);
      A = Ae2; BT = BTall + (size_t)1024 * KS; C = ZAh; ldc = NA;
    }
    int rowBase = bx * 128, colBase = by * 128;
    int mw = wid * 32;

    f32x4 acc[2][8];
    #pragma unroll
    for (int i = 0; i < 2; ++i)
      #pragma unroll
      for (int j = 0; j < 8; ++j) acc[i][j] = (f32x4){0.f, 0.f, 0.f, 0.f};

    int rowA0 = mw + l15, rowA1 = mw + 16 + l15;
    int sA0 = (l4 ^ ((rowA0 >> 1) & 3)) << 3;
    int sA1 = (l4 ^ ((rowA1 >> 1) & 3)) << 3;

    #pragma unroll 1
    for (int ks = 0; ks < 10; ++ks) {
      int k0 = ks * 32;
      #pragma unroll
      for (int j = 0; j < 2; ++j) {
        int idx = tid + j * 256;          // chunk id 0..511
        int r = idx >> 2, s = idx & 3;
        int sl = s ^ ((r >> 1) & 3);      // inverse-swizzled source slot
        int chunkStart = j * 256 + wid * 64;   // wave-uniform LDS base
        gl2lds16(A + (size_t)(rowBase + r) * KS + k0 + (sl << 3), &As[chunkStart * 8]);
        gl2lds16(BT + (size_t)(colBase + r) * KS + k0 + (sl << 3), &Bs[chunkStart * 8]);
      }
      __syncthreads();
      f16x8 a0 = *reinterpret_cast<const f16x8*>(&As[rowA0 * 32 + sA0]);
      f16x8 a1 = *reinterpret_cast<const f16x8*>(&As[rowA1 * 32 + sA1]);
      #pragma unroll
      for (int nj = 0; nj < 8; ++nj) {
        int rb = nj * 16 + l15;
        f16x8 bf = *reinterpret_cast<const f16x8*>(&Bs[rb * 32 + ((l4 ^ ((rb >> 1) & 3)) << 3)]);
        acc[0][nj] = __builtin_amdgcn_mfma_f32_16x16x32_f16(a0, bf, acc[0][nj], 0, 0, 0);
        acc[1][nj] = __builtin_amdgcn_mfma_f32_16x16x32_f16(a1, bf, acc[1][nj], 0, 0, 0);
      }
      __syncthreads();
    }
    #pragma unroll
    for (int mi = 0; mi < 2; ++mi) {
      int row0 = rowBase + mw + mi * 16 + l4 * 4;
      #pragma unroll
      for (int nj = 0; nj < 8; ++nj) {
        int col = colBase + nj * 16 + l15;
        #pragma unroll
        for (int r = 0; r < 4; ++r)
          C[(size_t)(row0 + r) * ldc + col] = f2h(acc[mi][nj][r]);
      }
    }
  } else {
    // ---- cosine job: per-b 64x64 MFMA tile ----
    int b = lin - 520;
    int rowBase = b * 40, colBase = b * 60;
    f32x4 cacc[4];
    #pragma unroll
    for (int nj = 0; nj < 4; ++nj) cacc[nj] = (f32x4){0.f, 0.f, 0.f, 0.f};
    int rowA = (wid << 4) + l15;
    int sA = (l4 ^ ((rowA >> 1) & 3)) << 3;

    #pragma unroll 1
    for (int ks = 0; ks < 10; ++ks) {
      int k0 = ks * 32;
      int r = tid >> 2, s = tid & 3;
      int sl = s ^ ((r >> 1) & 3);
      int chunkStart = wid * 64;            // 256 chunks: lane writes chunk tid
      int gr = rowBase + r; if (gr > 2559) gr = 2559;
      int gc = colBase + r; if (gc > 3839) gc = 3839;
      gl2lds16(Ae1 + (size_t)gr * KS + k0 + (sl << 3), &As[chunkStart * 8]);
      gl2lds16(Ae2 + (size_t)gc * KS + k0 + (sl << 3), &Bs[chunkStart * 8]);
      __syncthreads();
      f16x8 a0 = *reinterpret_cast<const f16x8*>(&As[rowA * 32 + sA]);
      #pragma unroll
      for (int nj = 0; nj < 4; ++nj) {
        int rb = (nj << 4) + l15;
        f16x8 bf = *reinterpret_cast<const f16x8*>(&Bs[rb * 32 + ((l4 ^ ((rb >> 1) & 3)) << 3)]);
        cacc[nj] = __builtin_amdgcn_mfma_f32_16x16x32_f16(a0, bf, cacc[nj], 0, 0, 0);
      }
      __syncthreads();
    }
    int q0 = (wid << 4) + l4 * 4;
    #pragma unroll
    for (int nj = 0; nj < 4; ++nj) {
      int a = (nj << 4) + l15;
      if (a >= ALn) continue;
      float nav = na[colBase + a];
      #pragma unroll
      for (int r = 0; r < 4; ++r) {
        int qq = q0 + r;
        if (qq < QLn) {
          float den = fmaxf(nq[rowBase + qq] * nav, 1e-6f);
          cosb[(size_t)(rowBase + qq) * ALn + a] = cacc[nj][r] / den;
        }
      }
    }
  }
}

// ============ pools (fp16 in, short2 col-pair loads, t-split across thread halves) ============
// bid [0,128): sm pool, 1 sentence per block
// bid [128,448): ctx pool, (b, qg of 8 q's) per block
__global__ __launch_bounds__(256) void k_pool(
    const short* __restrict__ ZQh, const short* __restrict__ ZAh,
    const float* __restrict__ convb, const float* __restrict__ cosb,
    const float* __restrict__ ctxb,
    float* __restrict__ pooled_part, float* __restrict__ pctx_part) {
  __shared__ float cl[8][ALn];
  int bid = blockIdx.x, tid = threadIdx.x;
  int cp = tid & 127, th = tid >> 7;
  int c2 = cp * 2;
  if (bid < 128) {
    int s = bid;
    const short* zb; int L, ld;
    if (s < Bn) { zb = ZQh + (size_t)s * QLn * NQ; L = QLn; ld = NQ; }
    else        { zb = ZAh + (size_t)(s - Bn) * ALn * NA; L = ALn; ld = NA; }
    int P = L - 2;
    int t0 = th * (P >> 1), t1 = (th ? P : (P >> 1));
    float b0 = convb[c2], b1 = convb[c2 + 1];
    float m0 = 0.f, m1 = 0.f;
    for (int t = t0; t < t1; ++t) {
      float2 v0 = h2x2(*(const unsigned int*)&zb[t * ld + c2]);
      float2 v1 = h2x2(*(const unsigned int*)&zb[(t + 1) * ld + 256 + c2]);
      float2 v2 = h2x2(*(const unsigned int*)&zb[(t + 2) * ld + 512 + c2]);
      m0 = fmaxf(m0, b0 + v0.x + v1.x + v2.x);
      m1 = fmaxf(m1, b1 + v0.y + v1.y + v2.y);
    }
    float* dst = pooled_part + ((size_t)th * 128 + s) * 256 + c2;
    dst[0] = m0; dst[1] = m1;
  } else {
    int g = bid - 128;
    int b = g / 5, q0 = (g % 5) * 8;
    int rq = b * QLn + q0;
    for (int i = tid; i < 8 * ALn; i += 256)
      cl[i / ALn][i % ALn] = cosb[(size_t)(rq + i / ALn) * ALn + (i % ALn)];
    __syncthreads();
    const short* zb = ZAh + (size_t)b * ALn * NA + 768;
    float b0 = ctxb[c2], b1 = ctxb[c2 + 1];
    float m[8][2];
    #pragma unroll
    for (int rr = 0; rr < 8; ++rr) { m[rr][0] = 0.f; m[rr][1] = 0.f; }
    int t0 = th * 29;
    for (int t = t0; t < t0 + 29; ++t) {
      float2 v0 = h2x2(*(const unsigned int*)&zb[t * NA + c2]);
      float2 v1 = h2x2(*(const unsigned int*)&zb[(t + 1) * NA + 256 + c2]);
      float2 v2 = h2x2(*(const unsigned int*)&zb[(t + 2) * NA + 512 + c2]);
      #pragma unroll
      for (int rr = 0; rr < 8; ++rr) {
        float c0 = cl[rr][t], c1 = cl[rr][t + 1], c2v = cl[rr][t + 2];
        m[rr][0] = fmaxf(m[rr][0], b0 + c0 * v0.x + c1 * v1.x + c2v * v2.x);
        m[rr][1] = fmaxf(m[rr][1], b1 + c0 * v0.y + c1 * v1.y + c2v * v2.y);
      }
    }
    #pragma unroll
    for (int rr = 0; rr < 8; ++rr) {
      float* dst = pctx_part + ((size_t)th * 2560 + rq + rr) * 256 + c2;
      dst[0] = m[rr][0]; dst[1] = m[rr][1];
    }
  }
}

// ============ fused: fc (32 blocks) | ctx-fc+attn-MLP+score+num/den (320 blocks) ============
__global__ __launch_bounds__(256) void k_fcattn(
    const float* __restrict__ pooled_part, const float* __restrict__ smfcW,
    const float* __restrict__ smfcb, const float* __restrict__ pctx_part,
    const short* __restrict__ ZQh, const float* __restrict__ Wcat,
    const float* __restrict__ bvec, const float* __restrict__ probW,
    float* __restrict__ feat_comb, float* __restrict__ numb, float* __restrict__ denb) {
  __shared__ float lds[10304];   // xin[2048] | wt[8192] | sred[64]
  int bid = blockIdx.x, j = threadIdx.x;
  if (bid < 32) {
    float* xin = lds;            // [256][4]
    float* wt  = lds + 1024;     // [32][256]
    int r0 = bid * 4;
    #pragma unroll
    for (int rr = 0; rr < 4; ++rr)
      xin[j * 4 + rr] = fmaxf(pooled_part[(size_t)(r0 + rr) * 256 + j],
                              pooled_part[(size_t)(128 + r0 + rr) * 256 + j]);
    float acc[4];
    #pragma unroll
    for (int rr = 0; rr < 4; ++rr) acc[rr] = smfcb[j];
    for (int ph = 0; ph < 8; ++ph) {
      const float4* src = (const float4*)(smfcW + (size_t)ph * 32 * 256);
      float4* dst = (float4*)wt;
      #pragma unroll
      for (int i = 0; i < 8; ++i) dst[i * 256 + j] = src[i * 256 + j];
      __syncthreads();
      #pragma unroll
      for (int kk = 0; kk < 32; ++kk) {
        float4 x = *reinterpret_cast<const float4*>(&xin[(ph * 32 + kk) * 4]);
        float wv = wt[kk * 256 + j];
        acc[0] += x.x * wv; acc[1] += x.y * wv; acc[2] += x.z * wv; acc[3] += x.w * wv;
      }
      __syncthreads();
    }
    #pragma unroll
    for (int rr = 0; rr < 4; ++rr) {
      int row = r0 + rr;
      feat_comb[(size_t)(row & 63) * 512 + ((row >> 6) * 256) + j] = acc[rr];
    }
  } else {
    float* xin  = lds;           // [256][8]
    float* wt   = lds + 2048;    // [16][512]
    float* sred = lds + 10240;   // [8][4]
    int g = bid - 32;
    int b = g / 5, q0 = (g % 5) * 8;
    int rq = b * QLn + q0;
    #pragma unroll
    for (int rr = 0; rr < 8; ++rr)
      xin[j * 8 + rr] = fmaxf(pctx_part[(size_t)(rq + rr) * 256 + j],
                              pctx_part[(size_t)(2560 + rq + rr) * 256 + j]);
    float hf[8], hh[8];
    float bf0 = bvec[j], bh0 = bvec[256 + j];
    #pragma unroll
    for (int rr = 0; rr < 8; ++rr) {
      hf[rr] = bf0;
      hh[rr] = bh0 + h2f(ZQh[(size_t)(rq + rr) * NQ + 768 + j]);
    }
    for (int ph = 0; ph < 16; ++ph) {
      const float4* src = (const float4*)(Wcat + (size_t)ph * 16 * 512);
      float4* dst = (float4*)wt;
      #pragma unroll
      for (int i = 0; i < 8; ++i) dst[i * 256 + j] = src[i * 256 + j];
      __syncthreads();
      #pragma unroll
      for (int kk = 0; kk < 16; ++kk) {
        int k = ph * 16 + kk;
        float4 x0 = *reinterpret_cast<const float4*>(&xin[k * 8]);
        float4 x1 = *reinterpret_cast<const float4*>(&xin[k * 8 + 4]);
        float w0 = wt[kk * 512 + j], w1 = wt[kk * 512 + 256 + j];
        hf[0] += x0.x * w0; hf[1] += x0.y * w0; hf[2] += x0.z * w0; hf[3] += x0.w * w0;
        hf[4] += x1.x * w0; hf[5] += x1.y * w0; hf[6] += x1.z * w0; hf[7] += x1.w * w0;
        hh[0] += x0.x * w1; hh[1] += x0.y * w1; hh[2] += x0.z * w1; hh[3] += x0.w * w1;
        hh[4] += x1.x * w1; hh[5] += x1.y * w1; hh[6] += x1.z * w1; hh[7] += x1.w * w1;
      }
      __syncthreads();
    }
    float pw = probW[j];
    int lane = j & 63, wv = j >> 6;
    #pragma unroll
    for (int rr = 0; rr < 8; ++rr) {
      float s = tanhf(hh[rr]) * pw;
      #pragma unroll
      for (int off = 32; off; off >>= 1) s += __shfl_down(s, off, 64);
      if (lane == 0) sred[rr * 4 + wv] = s;
    }
    __syncthreads();
    float e[8], esum = 0.f, acc3 = 0.f;
    #pragma unroll
    for (int rr = 0; rr < 8; ++rr) {
      float s = sred[rr * 4] + sred[rr * 4 + 1] + sred[rr * 4 + 2] + sred[rr * 4 + 3];
      e[rr] = __expf(s);       // |s| <= sum|probW| ~ 4: safe without max-sub
      esum += e[rr];
      acc3 += e[rr] * hf[rr];
    }
    atomicAdd(&numb[(size_t)b * 256 + j], acc3);
    if (j == 0) atomicAdd(&denb[b], esum);
  }
}

// ============ fused W1(+feature3 via num/den) + BN + tanh + head (last block) ============
__global__ __launch_bounds__(256) void k_w1bn(
    const float* __restrict__ feat_comb, const float* __restrict__ numb,
    const float* __restrict__ denb, const float* __restrict__ W1,
    const float* __restrict__ b1, const float* __restrict__ gamma,
    const float* __restrict__ beta, const float* __restrict__ W2,
    const float* __restrict__ b2, float* __restrict__ feat_out,
    float* __restrict__ preds, float* __restrict__ logits, int* __restrict__ done) {
  int j0 = blockIdx.x * 8;
  int tid = threadIdx.x;
  __shared__ float wl[768][12];
  __shared__ float hb[64][8];
  __shared__ int lastflag;
  for (int it = 0; it < 24; ++it) {
    int idx = tid + it * 256;
    int k = idx >> 3, jj = idx & 7;
    wl[k][jj] = W1[(size_t)k * 512 + j0 + jj];
  }
  __syncthreads();
  int n = tid >> 2, p = tid & 3;
  float acc1[8] = {0.f, 0.f, 0.f, 0.f, 0.f, 0.f, 0.f, 0.f};
  float acc2[8] = {0.f, 0.f, 0.f, 0.f, 0.f, 0.f, 0.f, 0.f};
  const float* frow = feat_comb + (size_t)n * 512 + p;
  for (int i = 0; i < 128; ++i) {
    float v = frow[i * 4];
    int k = p + i * 4;
    float4 w0 = *reinterpret_cast<const float4*>(&wl[k][0]);
    float4 w1v = *reinterpret_cast<const float4*>(&wl[k][4]);
    acc1[0] += v * w0.x; acc1[1] += v * w0.y; acc1[2] += v * w0.z; acc1[3] += v * w0.w;
    acc1[4] += v * w1v.x; acc1[5] += v * w1v.y; acc1[6] += v * w1v.z; acc1[7] += v * w1v.w;
  }
  const float* nrow = numb + (size_t)n * 256 + p;
  for (int i = 0; i < 64; ++i) {
    float v = nrow[i * 4];
    int k = 512 + p + i * 4;
    float4 w0 = *reinterpret_cast<const float4*>(&wl[k][0]);
    float4 w1v = *reinterpret_cast<const float4*>(&wl[k][4]);
    acc2[0] += v * w0.x; acc2[1] += v * w0.y; acc2[2] += v * w0.z; acc2[3] += v * w0.w;
    acc2[4] += v * w1v.x; acc2[5] += v * w1v.y; acc2[6] += v * w1v.z; acc2[7] += v * w1v.w;
  }
  #pragma unroll
  for (int jj = 0; jj < 8; ++jj) {
    acc1[jj] += __shfl_xor(acc1[jj], 1, 64);
    acc1[jj] += __shfl_xor(acc1[jj], 2, 64);
    acc2[jj] += __shfl_xor(acc2[jj], 1, 64);
    acc2[jj] += __shfl_xor(acc2[jj], 2, 64);
  }
  if (p == 0) {
    float rden = 1.f / denb[n];
    #pragma unroll
    for (int jj = 0; jj < 8; ++jj) hb[n][jj] = acc1[jj] + rden * acc2[jj] + b1[j0 + jj];
  }
  __syncthreads();
  if (tid < 64) {
    float l0p = 0.f, l1p = 0.f;
    #pragma unroll
    for (int jj = 0; jj < 8; ++jj) {
      float v = hb[tid][jj];
      float s = v;
      #pragma unroll
      for (int off = 32; off; off >>= 1) s += __shfl_xor(s, off, 64);
      float mu = s * (1.f / 64.f);
      float d = v - mu;
      float q2 = d * d;
      #pragma unroll
      for (int off = 32; off; off >>= 1) q2 += __shfl_xor(q2, off, 64);
      float var = q2 * (1.f / 64.f);
      float fo = tanhf(d * rsqrtf(var + 1e-5f) * gamma[j0 + jj] + beta[j0 + jj]);
      feat_out[(size_t)tid * 512 + j0 + jj] = fo;
      l0p += fo * W2[(j0 + jj) * 2 + 0];
      l1p += fo * W2[(j0 + jj) * 2 + 1];
    }
    atomicAdd(&logits[tid * 2 + 0], l0p);
    atomicAdd(&logits[tid * 2 + 1], l1p);
  }
  __threadfence();
  __syncthreads();
  if (tid == 0) lastflag = (atomicAdd(done, 1) == gridDim.x - 1) ? 1 : 0;
  __syncthreads();
  if (lastflag && tid < 64) {
    __threadfence();
    float l0 = atomicAdd(&logits[tid * 2 + 0], 0.f) + b2[0];
    float l1 = atomicAdd(&logits[tid * 2 + 1], 0.f) + b2[1];
    float mx = fmaxf(l0, l1);
    float lse = mx + logf(__expf(l0 - mx) + __expf(l1 - mx));
    preds[tid * 2 + 0] = l0 - lse;
    preds[tid * 2 + 1] = l1 - lse;
  }
}

extern "C" void kernel_launch(void* const* d_in, const int* in_sizes, int n_in,
                              void* d_out, int out_size, void* d_ws, size_t ws_size,
                              hipStream_t stream) {
  (void)in_sizes; (void)n_in; (void)out_size; (void)ws_size;
  const int*   question  = (const int*)d_in[0];
  const int*   answer    = (const int*)d_in[1];
  const float* embedding = (const float*)d_in[3];
  const float* sm_convW  = (const float*)d_in[4];
  const float* sm_convb  = (const float*)d_in[5];
  const float* sm_fcW    = (const float*)d_in[6];
  const float* sm_fcb    = (const float*)d_in[7];
  const float* ctx_convW = (const float*)d_in[8];
  const float* ctx_convb = (const float*)d_in[9];
  const float* ctx_fcW   = (const float*)d_in[10];
  const float* ctx_fcb   = (const float*)d_in[11];
  const float* attnW     = (const float*)d_in[12];
  const float* attnb     = (const float*)d_in[13];
  const float* probW     = (const float*)d_in[14];
  const float* W1        = (const float*)d_in[15];
  const float* b1        = (const float*)d_in[16];
  const float* gamma     = (const float*)d_in[17];
  const float* beta      = (const float*)d_in[18];
  const float* W2        = (const float*)d_in[19];
  const float* b2        = (const float*)d_in[20];

  float* out = (float*)d_out;   // [0:128) preds, [128:) feat_out 64x512
  char* base = (char*)d_ws;
  size_t off = 0;
  auto alloc = [&](size_t bytes) { char* p = base + off; off += (bytes + 255) & ~(size_t)255; return p; };

  short* Ae1   = (short*)alloc(2560ull * KS * 2);      // 1.64 MB (fp16)
  short* Ae2   = (short*)alloc(3840ull * KS * 2);      // 2.46 MB
  short* BTall = (short*)alloc(2560ull * KS * 2);      // 1.64 MB; dead after k_mega
  short* ZQh   = (short*)alloc(2560ull * NQ * 2);      // 5.24 MB (fp16)
  short* ZAh   = (short*)alloc(3840ull * NA * 2);      // 11.8 MB (fp16)
  float* nq    = (float*)alloc(2560 * 4);
  float* na    = (float*)alloc(3840 * 4);
  float* cosb  = (float*)alloc(2560ull * ALn * 4);
  float* Wcat  = (float*)alloc(256ull * 512 * 4);
  float* bvec  = (float*)alloc(512 * 4);
  float* pctx_part = (float*)alloc(2ull * 2560 * 256 * 4);   // 5.24 MB
  float* feat_comb = (float*)alloc(64ull * 512 * 4);
  float* numb   = (float*)alloc(64ull * 256 * 4);
  float* denb   = (float*)alloc(64 * 4);
  float* logits = (float*)alloc(128 * 4);
  int*   done   = (int*)alloc(256);
  float* pooled_part = (float*)BTall;                  // overlay (dead after k_mega)

  // 1. prep: gather+norms | BT-transpose | Wcat | zero-accumulators (2058 blocks)
  k_prep<<<2058, 256, 0, stream>>>(question, answer, embedding, sm_convW, ctx_convW,
                                   attnW, ctx_fcW, ctx_fcb, attnb,
                                   Ae1, Ae2, nq, na, BTall, Wcat, bvec,
                                   numb, denb, logits, done);
  // 2. split mega GEMM (fp16, K=320) + MFMA cosine (584 blocks)
  k_mega<<<584, 256, 0, stream>>>(Ae1, Ae2, BTall, ZQh, ZAh, nq, na, cosb);
  // 3. pools: sm (128) | ctx (320) — short2 col-pair loads, t-split in-block
  k_pool<<<448, 256, 0, stream>>>(ZQh, ZAh, sm_convb, cosb, ctx_convb,
                                  pooled_part, pctx_part);
  // 4. fc | ctx-fc + attn + score + softmax num/den (352 blocks)
  k_fcattn<<<352, 256, 0, stream>>>(pooled_part, sm_fcW, sm_fcb, pctx_part,
                                    ZQh, Wcat, bvec, probW,
                                    feat_comb, numb, denb);
  // 5. W1 + feature3 + BN + tanh + head (64 blocks, last-block log_softmax)
  k_w1bn<<<64, 256, 0, stream>>>(feat_comb, numb, denb, W1, b1, gamma, beta,
                                 W2, b2, out + 128, out, logits, done);
}